// Round 16
// baseline (231.297 us; speedup 1.0000x reference)
//
#include <hip/hip_runtime.h>
#include <hip/hip_bf16.h>
#include <math.h>

// Problem constants: B=1, N=4096, C=768, H=12, HD=64
#define LOG2E 1.44269504088896340736f

typedef short bf16x8 __attribute__((ext_vector_type(8)));
typedef float f32x4 __attribute__((ext_vector_type(4)));

static __device__ __forceinline__ float bf2f(ushort u){
  union { float f; unsigned int u; } x; x.u = ((unsigned int)u) << 16; return x.f;
}
static __device__ __forceinline__ ushort f2bf(float f){
  union { float f; unsigned int u; } x; x.f = f;
  unsigned int r = x.u + 0x7fffu + ((x.u >> 16) & 1u);   // RNE
  return (ushort)(r >> 16);
}
static __device__ __forceinline__ unsigned cvt_pk_bf16(float a, float b){
  unsigned r;
  asm("v_cvt_pk_bf16_f32 %0, %1, %2" : "=v"(r) : "v"(a), "v"(b));
  return r;   // lo = bf16(a), hi = bf16(b)
}
static __device__ __forceinline__ float fmax3(float a, float b, float c){
  return fmaxf(fmaxf(a, b), c);   // clang fuses to v_max3_f32
}
// tanh-form GELU, clamped so exp2 arg is bounded (provably finite for ALL inputs).
static __device__ __forceinline__ float gelu_fast(float v){
  float u = v + 0.044715f * v * v * v;
  u = fminf(u, 30.0f);
  float e = exp2f(2.3021187f * u);
  float inv = 1.0f / (e + 1.0f);
  return v - v * inv;
}
// lane <-> lane^1 exchange via DPP quad_perm [1,0,3,2] — pure VALU, no LDS
static __device__ __forceinline__ float dpp_xor1(float v){
  int i = __builtin_amdgcn_mov_dpp(__float_as_int(v), 0xB1, 0xF, 0xF, true);
  return __int_as_float(i);
}
// async global->LDS, 16B per lane; LDS dest = wave-uniform base + lane*16
static __device__ __forceinline__ void gload_lds16(const void* g, void* l){
  __builtin_amdgcn_global_load_lds(
      (const __attribute__((address_space(1))) unsigned int*)g,
      (__attribute__((address_space(3))) unsigned int*)l, 16, 0, 0);
}

// ---------------- fp32 -> bf16 weight conversion (all 4 weights, one kernel) ----------------
__global__ __launch_bounds__(256) void cvt_all(const float* __restrict__ s0, ushort* __restrict__ d0, int c0,
                                               const float* __restrict__ s1, ushort* __restrict__ d1, int c1,
                                               const float* __restrict__ s2, ushort* __restrict__ d2, int c2,
                                               const float* __restrict__ s3, ushort* __restrict__ d3, int c3){
  int j = blockIdx.x * 256 + threadIdx.x;
  const float* s; ushort* d;
  if (j < c0){ s = s0; d = d0; }
  else { j -= c0;
    if (j < c1){ s = s1; d = d1; }
    else { j -= c1;
      if (j < c2){ s = s2; d = d2; }
      else { j -= c2; if (j >= c3) return; s = s3; d = d3; } } }
  float4 v = ((const float4*)s)[j];
  ushort4 o;
  o.x = f2bf(v.x); o.y = f2bf(v.y); o.z = f2bf(v.z); o.w = f2bf(v.w);
  ((ushort4*)d)[j] = o;
}

// ---------------- LayerNorm (fp32 OR bf16 in -> bf16 out), one WAVE per row of 768 ----------------
template<typename T>
__global__ __launch_bounds__(256) void ln_kernel(const T* __restrict__ x,
                                                 const float* __restrict__ g,
                                                 const float* __restrict__ bta,
                                                 ushort* __restrict__ out){
  int w = threadIdx.x >> 6, l = threadIdx.x & 63;
  int row = blockIdx.x * 4 + w;
  const T* xr = x + (size_t)row * 768;
  f32x4 v[3];
  #pragma unroll
  for (int i = 0; i < 3; ++i){
    if constexpr (sizeof(T) == 4){
      v[i] = *(const f32x4*)(xr + i * 256 + l * 4);
    } else {
      ushort4 u = *(const ushort4*)(xr + i * 256 + l * 4);
      v[i][0] = bf2f(u.x); v[i][1] = bf2f(u.y); v[i][2] = bf2f(u.z); v[i][3] = bf2f(u.w);
    }
  }
  float s = 0.0f;
  #pragma unroll
  for (int i = 0; i < 3; ++i)
    #pragma unroll
    for (int r = 0; r < 4; ++r) s += v[i][r];
  #pragma unroll
  for (int off = 32; off; off >>= 1) s += __shfl_xor(s, off, 64);
  float mu = s * (1.0f / 768.0f);
  float q = 0.0f;
  #pragma unroll
  for (int i = 0; i < 3; ++i)
    #pragma unroll
    for (int r = 0; r < 4; ++r){ float d = v[i][r] - mu; q += d * d; }
  #pragma unroll
  for (int off = 32; off; off >>= 1) q += __shfl_xor(q, off, 64);
  float rs = rsqrtf(q * (1.0f / 768.0f) + 1e-5f);
  ushort* orow = out + (size_t)row * 768;
  #pragma unroll
  for (int i = 0; i < 3; ++i){
    f32x4 gg = *(const f32x4*)(g + i * 256 + l * 4);
    f32x4 bb = *(const f32x4*)(bta + i * 256 + l * 4);
    ushort4 o;
    o.x = f2bf((v[i][0] - mu) * rs * gg[0] + bb[0]);
    o.y = f2bf((v[i][1] - mu) * rs * gg[1] + bb[1]);
    o.z = f2bf((v[i][2] - mu) * rs * gg[2] + bb[2]);
    o.w = f2bf((v[i][3] - mu) * rs * gg[3] + bb[3]);
    *(ushort4*)(orow + i * 256 + l * 4) = o;
  }
}

// ---------------- generic bf16 MFMA GEMM: C[M,N] = A[M,K(+koff)] * B[N,K(+koff)]^T ----------------
// 128x128 tile, BK=64, 4 waves (2x2), DOUBLE-BUFFERED raw-barrier pipeline (round-15 win):
// stage(k+1) before compute(k); explicit asm waitcnt AFTER compute; raw s_barrier (no auto drain).
// MODE 0: bf16(C). MODE 1: fp32(C+bias+res). MODE 2: bf16(gelu_fast(C+bias)).
// MODE 3: fp32 partial (split-K). MODE 4: fused RoPE + Q/K/Vt scatter. MODE 5: bf16 partial (split-K).
// MODE 6: bf16(C + bias + fp32 res)
template<int MODE>
__global__ __launch_bounds__(256) void gemm_bf16(const ushort* __restrict__ A, int lda,
                                                 const ushort* __restrict__ Bm, int ldb,
                                                 int K,
                                                 const float* __restrict__ bias,
                                                 const float* __restrict__ res, int ldr,
                                                 void* __restrict__ out, int ldo,
                                                 const float* __restrict__ fc,
                                                 const float* __restrict__ fs,
                                                 ushort* __restrict__ Qs,
                                                 ushort* __restrict__ Ks,
                                                 ushort* __restrict__ Vt){
  __shared__ __align__(16) ushort As[2][128 * 64];
  __shared__ __align__(16) ushort Bs[2][128 * 64];
  const int tid = threadIdx.x;
  const int m0 = blockIdx.x * 128, n0 = blockIdx.y * 128;
  const int w = tid >> 6, l = tid & 63;
  const int wm = (w >> 1) * 64, wn = (w & 1) * 64;
  const int lr = l & 15, lg = l >> 4;
  const int lane8 = l >> 3, sl = l & 7;
  const int koff = (MODE == 3 || MODE == 5) ? blockIdx.z * K : 0;

  f32x4 acc[4][4] = {};

  auto stage = [&](int k0, int b){
    #pragma unroll
    for (int j = 0; j < 4; ++j){
      int instr = w * 4 + j;               // 0..15, 1KB each
      int row = instr * 8 + lane8;         // 0..127
      gload_lds16((const char*)A + ((size_t)(m0 + row) * lda + koff + k0) * 2 + ((sl ^ (row & 7)) << 4),
                  (char*)&As[b][0] + instr * 1024);
      gload_lds16((const char*)Bm + ((size_t)(n0 + row) * ldb + koff + k0) * 2 + ((sl ^ (row & 7)) << 4),
                  (char*)&Bs[b][0] + instr * 1024);
    }
  };

  const int nk = K >> 6;
  stage(0, 0);
  asm volatile("s_waitcnt vmcnt(0)" ::: "memory");
  __builtin_amdgcn_s_barrier();

  #pragma unroll 1
  for (int ki = 0; ki < nk; ++ki){
    const int b = ki & 1;
    if (ki + 1 < nk) stage((ki + 1) << 6, b ^ 1);
    #pragma unroll
    for (int kk = 0; kk < 2; ++kk){
      bf16x8 af[4], bfr[4];
      #pragma unroll
      for (int mi = 0; mi < 4; ++mi){
        int row = wm + mi * 16 + lr;
        int cg = (kk * 4 + lg) ^ (row & 7);
        af[mi] = *(const bf16x8*)(&As[b][0] + row * 64 + cg * 8);
      }
      #pragma unroll
      for (int nj = 0; nj < 4; ++nj){
        int row = wn + nj * 16 + lr;
        int cg = (kk * 4 + lg) ^ (row & 7);
        bfr[nj] = *(const bf16x8*)(&Bs[b][0] + row * 64 + cg * 8);
      }
      #pragma unroll
      for (int mi = 0; mi < 4; ++mi)
        #pragma unroll
        for (int nj = 0; nj < 4; ++nj)
          acc[mi][nj] = __builtin_amdgcn_mfma_f32_16x16x32_bf16(af[mi], bfr[nj], acc[mi][nj], 0, 0, 0);
    }
    asm volatile("s_waitcnt vmcnt(0) lgkmcnt(0)" ::: "memory");
    __builtin_amdgcn_s_barrier();
  }

  const size_t zout = (MODE == 3 || MODE == 5) ? (size_t)blockIdx.z * gridDim.x * 128 * ldo : 0;

  if (MODE == 4){
    // fused RoPE + QKV scatter. col = n0+wn+nj*16+lr in [0,2304); part uniform per block
    const int part = n0 / 768;                    // 0=q, 1=k, 2=v
    const float qsc = 0.125f * LOG2E;
    #pragma unroll
    for (int mi = 0; mi < 4; ++mi){
      const int n_base = m0 + wm + mi * 16 + lg * 4;
      #pragma unroll
      for (int nj = 0; nj < 4; ++nj){
        const int col = n0 + wn + nj * 16 + lr;
        const int head = (col - part * 768) >> 6;
        const int d = col & 63;
        if (part == 2){
          ushort4 pk;
          pk.x = f2bf(acc[mi][nj][0]); pk.y = f2bf(acc[mi][nj][1]);
          pk.z = f2bf(acc[mi][nj][2]); pk.w = f2bf(acc[mi][nj][3]);
          *(ushort4*)(Vt + ((size_t)head * 64 + d) * 4096 + n_base) = pk;
        } else {
          const int p = d >> 1;
          ushort* dst = (part == 0) ? Qs : Ks;
          #pragma unroll
          for (int r = 0; r < 4; ++r){
            int n = n_base + r;
            float v = acc[mi][nj][r];
            float pv = dpp_xor1(v);               // partner element (col^1)
            float c = fc[(size_t)n * 32 + p];
            float sv = fs[(size_t)n * 32 + p];
            float rr = v * c + pv * ((d & 1) ? sv : -sv);
            if (part == 0) rr *= qsc;
            dst[((size_t)head * 4096 + n) * 64 + d] = f2bf(rr);
          }
        }
      }
    }
    return;
  }

  // epilogue: D layout row=(lane>>4)*4+reg, col=lane&15 (m89-verified)
  #pragma unroll
  for (int mi = 0; mi < 4; ++mi){
    #pragma unroll
    for (int nj = 0; nj < 4; ++nj){
      #pragma unroll
      for (int r = 0; r < 4; ++r){
        int grow = m0 + wm + mi * 16 + lg * 4 + r;
        int gcol = n0 + wn + nj * 16 + lr;
        float v = acc[mi][nj][r];
        if (MODE == 0){
          ((ushort*)out)[(size_t)grow * ldo + gcol] = f2bf(v);
        } else if (MODE == 1){
          v += bias[gcol] + res[(size_t)grow * ldr + gcol];
          ((float*)out)[(size_t)grow * ldo + gcol] = v;
        } else if (MODE == 2){
          v = gelu_fast(v + bias[gcol]);
          ((ushort*)out)[(size_t)grow * ldo + gcol] = f2bf(v);
        } else if (MODE == 3){
          ((float*)out)[zout + (size_t)grow * ldo + gcol] = v;
        } else if (MODE == 5){
          ((ushort*)out)[zout + (size_t)grow * ldo + gcol] = f2bf(v);
        } else {
          v += bias[gcol] + res[(size_t)grow * ldr + gcol];
          ((ushort*)out)[(size_t)grow * ldo + gcol] = f2bf(v);
        }
      }
    }
  }
}

// ---------------- split-K=4 GEMM combine (bf16 partials + bf16 residual): out fp32 ----------------
__global__ __launch_bounds__(192) void gemm_combine4_bf16(const ushort* __restrict__ parts,
                                                          const float* __restrict__ bias,
                                                          const ushort* __restrict__ res,
                                                          float* __restrict__ out){
  int q = blockIdx.x, t = threadIdx.x;
  size_t idx = (size_t)q * 768 + t * 4;
  const size_t seg = (size_t)4096 * 768;
  f32x4 o = {};
  #pragma unroll
  for (int s = 0; s < 4; ++s){
    ushort4 p = *(const ushort4*)(parts + s * seg + idx);
    o[0] += bf2f(p.x); o[1] += bf2f(p.y); o[2] += bf2f(p.z); o[3] += bf2f(p.w);
  }
  f32x4 b = *(const f32x4*)(bias + t * 4);
  ushort4 rr4 = *(const ushort4*)(res + idx);
  o[0] += b[0] + bf2f(rr4.x);
  o[1] += b[1] + bf2f(rr4.y);
  o[2] += b[2] + bf2f(rr4.z);
  o[3] += b[3] + bf2f(rr4.w);
  *(f32x4*)(out + idx) = o;
}

// ---------------- flash attention, split-K=2: grid (32, 12, 2), 4 waves x 32 q-rows ----------------
// QK^T C pre-initialized to -m_prev (defer-max); __all(lane_max <= 8) defer check (no shuffles);
// row-sum via mfma(ones, P); fp32 O partials (25MB, half of split-4); s_setprio around MFMA.
__global__ __launch_bounds__(256, 4) void flash_attn(const ushort* __restrict__ Qs,
                                                     const ushort* __restrict__ Ks,
                                                     const ushort* __restrict__ Vt,
                                                     float* __restrict__ Opart,
                                                     float* __restrict__ Ml){
  __shared__ __align__(16) char smem[32768];   // 2 bufs x (K 8KB + V 8KB)
  const int h = blockIdx.y, kh = blockIdx.z;
  const int w = threadIdx.x >> 6, l = threadIdx.x & 63;
  const int lr = l & 15, lg = l >> 4;
  const int lane8 = l >> 3, sl = l & 7;
  const int q0 = blockIdx.x * 128 + w * 32;
  const ushort* Qh = Qs + (size_t)h * (4096 * 64);
  const char* Kh = (const char*)(Ks + (size_t)h * (4096 * 64));
  const char* Vh = (const char*)(Vt + (size_t)h * (64 * 4096));

  bf16x8 qa[2][2];
  #pragma unroll
  for (int qf = 0; qf < 2; ++qf)
    #pragma unroll
    for (int kk = 0; kk < 2; ++kk)
      qa[qf][kk] = *(const bf16x8*)(Qh + (size_t)(q0 + qf * 16 + lr) * 64 + kk * 32 + lg * 8);

  // staging bases (inverse-swizzled source, T21); kh selects the 2048-key segment
  const char* kbase = Kh + (size_t)(kh * 2048 + w * 16 + lane8) * 128;
  const char* vbase = Vh + (size_t)(w * 16 + lane8) * 8192 + kh * 4096 + ((sl ^ lane8) << 4);
  int koff[2];
  #pragma unroll
  for (int j = 0; j < 2; ++j)
    koff[j] = j * 1024 + ((sl ^ ((lane8 & 3) | (((w * 2 + j) & 1) << 2))) << 4);

  // LDS read offsets (hoisted; K swizzle slot is t-independent)
  const int a_ = lr >> 2, b_ = lr & 3;
  const int krow = 8 * a_ + b_;                 // permuted K-row base
  const int f_ = b_ | ((a_ & 1) << 2);
  const int kslot0 = (lg ^ f_) << 4;
  const int kslot1 = ((4 + lg) ^ f_) << 4;
  const int vslot0 = lr * 128 + ((lg ^ (lr & 7)) << 4);
  const int vslot1 = lr * 128 + (((4 + lg) ^ (lr & 7)) << 4);

  f32x4 oacc[2][4] = {};        // C[d = db*16 + 4lg + r][q = lr] per qf
  f32x4 lacc[2] = {};           // row-sum accumulator
  float m_prev[2] = {0.0f, 0.0f};
  union { unsigned u[4]; bf16x8 v; } ones;
  #pragma unroll
  for (int i = 0; i < 4; ++i) ones.u[i] = 0x3F803F80u;

  auto stage = [&](int tile, char* Kb, char* Vb){
    #pragma unroll
    for (int j = 0; j < 2; ++j){
      gload_lds16(kbase + (size_t)tile * 8192 + koff[j], Kb + (w * 2 + j) * 1024);
      gload_lds16(vbase + (size_t)j * 65536 + (size_t)tile * 128, Vb + (w * 2 + j) * 1024);
    }
  };

  auto compute = [&](const char* Kb, const char* Vb, bool first){
    f32x4 sh[2][4];
    #pragma unroll
    for (int qf = 0; qf < 2; ++qf){
      float iv = first ? 0.0f : -m_prev[qf];
      #pragma unroll
      for (int t = 0; t < 4; ++t){
        sh[qf][t][0] = iv; sh[qf][t][1] = iv; sh[qf][t][2] = iv; sh[qf][t][3] = iv;
      }
    }
    __builtin_amdgcn_s_setprio(1);
    #pragma unroll
    for (int t = 0; t < 4; ++t){
      const char* kr = Kb + (krow + 4 * (t & 1) + 32 * (t >> 1)) * 128;
      bf16x8 k0 = *(const bf16x8*)(kr + kslot0);
      bf16x8 k1 = *(const bf16x8*)(kr + kslot1);
      #pragma unroll
      for (int qf = 0; qf < 2; ++qf){
        sh[qf][t] = __builtin_amdgcn_mfma_f32_16x16x32_bf16(k0, qa[qf][0], sh[qf][t], 0, 0, 0);
        sh[qf][t] = __builtin_amdgcn_mfma_f32_16x16x32_bf16(k1, qa[qf][1], sh[qf][t], 0, 0, 0);
      }
    }
    __builtin_amdgcn_s_setprio(0);
    // lane-local max per qf (16 values, 7 max ops) — no shuffles
    float mb[2];
    #pragma unroll
    for (int qf = 0; qf < 2; ++qf){
      float m1 = fmax3(sh[qf][0][0], sh[qf][0][1], sh[qf][0][2]);
      float m2 = fmax3(sh[qf][0][3], sh[qf][1][0], sh[qf][1][1]);
      float m3 = fmax3(sh[qf][1][2], sh[qf][1][3], sh[qf][2][0]);
      float m4 = fmax3(sh[qf][2][1], sh[qf][2][2], sh[qf][2][3]);
      float m5 = fmax3(sh[qf][3][0], sh[qf][3][1], sh[qf][3][2]);
      mb[qf] = fmax3(fmaxf(m1, m2), fmax3(m3, m4, m5), sh[qf][3][3]);
    }
    if (first){
      #pragma unroll
      for (int qf = 0; qf < 2; ++qf){
        float mm = fmaxf(mb[qf], __shfl_xor(mb[qf], 16, 64));
        mm = fmaxf(mm, __shfl_xor(mm, 32, 64));
        m_prev[qf] = mm;
        #pragma unroll
        for (int t = 0; t < 4; ++t)
          #pragma unroll
          for (int r = 0; r < 4; ++r) sh[qf][t][r] -= mm;
      }
    } else if (!__all(mb[0] <= 8.0f && mb[1] <= 8.0f)){
      #pragma unroll
      for (int qf = 0; qf < 2; ++qf){
        float mm = fmaxf(mb[qf], __shfl_xor(mb[qf], 16, 64));
        mm = fmaxf(mm, __shfl_xor(mm, 32, 64));
        float d = (mm > 8.0f) ? mm : 0.0f;       // sh already = S - m_prev
        float sc = exp2f(-d);
        #pragma unroll
        for (int t = 0; t < 4; ++t)
          #pragma unroll
          for (int r = 0; r < 4; ++r) sh[qf][t][r] -= d;
        #pragma unroll
        for (int db = 0; db < 4; ++db)
          #pragma unroll
          for (int r = 0; r < 4; ++r) oacc[qf][db][r] *= sc;
        #pragma unroll
        for (int r = 0; r < 4; ++r) lacc[qf][r] *= sc;
        m_prev[qf] += d;
      }
    }
    #pragma unroll
    for (int qf = 0; qf < 2; ++qf)
      #pragma unroll
      for (int t = 0; t < 4; ++t)
        #pragma unroll
        for (int r = 0; r < 4; ++r)
          sh[qf][t][r] = exp2f(sh[qf][t][r]);     // Q pre-scaled by log2e
    #pragma unroll
    for (int kk = 0; kk < 2; ++kk){
      union { unsigned u[4]; bf16x8 v; } pf[2];
      #pragma unroll
      for (int qf = 0; qf < 2; ++qf){
        pf[qf].u[0] = cvt_pk_bf16(sh[qf][2*kk][0],   sh[qf][2*kk][1]);
        pf[qf].u[1] = cvt_pk_bf16(sh[qf][2*kk][2],   sh[qf][2*kk][3]);
        pf[qf].u[2] = cvt_pk_bf16(sh[qf][2*kk+1][0], sh[qf][2*kk+1][1]);
        pf[qf].u[3] = cvt_pk_bf16(sh[qf][2*kk+1][2], sh[qf][2*kk+1][3]);
      }
      const int vs = kk ? vslot1 : vslot0;
      __builtin_amdgcn_s_setprio(1);
      #pragma unroll
      for (int db = 0; db < 4; ++db){
        bf16x8 vf = *(const bf16x8*)(Vb + vs + db * 2048);
        #pragma unroll
        for (int qf = 0; qf < 2; ++qf)
          oacc[qf][db] = __builtin_amdgcn_mfma_f32_16x16x32_bf16(vf, pf[qf].v, oacc[qf][db], 0, 0, 0);
      }
      #pragma unroll
      for (int qf = 0; qf < 2; ++qf)
        lacc[qf] = __builtin_amdgcn_mfma_f32_16x16x32_bf16(ones.v, pf[qf].v, lacc[qf], 0, 0, 0);
      __builtin_amdgcn_s_setprio(0);
    }
  };

  char* K0 = smem;          char* V0 = smem + 8192;
  char* K1 = smem + 16384;  char* V1 = smem + 24576;

  stage(0, K0, V0);
  __syncthreads();
  stage(1, K1, V1);
  compute(K0, V0, true);
  __syncthreads();
  stage(2, K0, V0);
  compute(K1, V1, false);
  __syncthreads();
  #pragma unroll 1
  for (int it2 = 1; it2 < 16; ++it2){            // 32 tiles = 2048 keys per segment
    stage(2 * it2 + 1, K1, V1);
    compute(K0, V0, false);
    __syncthreads();
    if (it2 < 15) stage(2 * it2 + 2, K0, V0);
    compute(K1, V1, false);
    __syncthreads();
  }

  #pragma unroll
  for (int qf = 0; qf < 2; ++qf){
    int q = q0 + qf * 16 + lr;
    float* Op = Opart + ((size_t)(kh * 12 + h) * 4096 + q) * 64;
    #pragma unroll
    for (int db = 0; db < 4; ++db)
      *(f32x4*)(Op + db * 16 + 4 * lg) = oacc[qf][db];
    if (lg == 0){
      float2 ml; ml.x = m_prev[qf]; ml.y = lacc[qf][0];
      *(float2*)(Ml + ((size_t)(kh * 12 + h) * 4096 + q) * 2) = ml;
    }
  }
}

// ---------------- split-K=2 attention combine (fp32 partials) ----------------
__global__ __launch_bounds__(192) void attn_combine(const float* __restrict__ Opart,
                                                    const float* __restrict__ Ml,
                                                    ushort* __restrict__ O){
  int q = blockIdx.x, t = threadIdx.x;           // t in [0,192): h = t>>4, d = (t&15)*4
  int h = t >> 4;
  float2 ml[2];
  #pragma unroll
  for (int s = 0; s < 2; ++s)
    ml[s] = *(const float2*)(Ml + ((size_t)(s * 12 + h) * 4096 + q) * 2);
  float m = fmaxf(ml[0].x, ml[1].x);
  float w0 = exp2f(ml[0].x - m), w1 = exp2f(ml[1].x - m);
  float inv = 1.0f / (ml[0].y * w0 + ml[1].y * w1);
  int dd = (t & 15) * 4;
  f32x4 o0 = *(const f32x4*)(Opart + ((size_t)h * 4096 + q) * 64 + dd);
  f32x4 o1 = *(const f32x4*)(Opart + ((size_t)(12 + h) * 4096 + q) * 64 + dd);
  uint2 ov;
  ov.x = cvt_pk_bf16((o0[0]*w0 + o1[0]*w1) * inv, (o0[1]*w0 + o1[1]*w1) * inv);
  ov.y = cvt_pk_bf16((o0[2]*w0 + o1[2]*w1) * inv, (o0[3]*w0 + o1[3]*w1) * inv);
  *(uint2*)(O + (size_t)q * 768 + t * 4) = ov;
}

// ---------------- launch ----------------
extern "C" void kernel_launch(void* const* d_in, const int* in_sizes, int n_in,
                              void* d_out, int out_size, void* d_ws, size_t ws_size,
                              hipStream_t stream){
  const float* x      = (const float*)d_in[0];
  const float* fcos   = (const float*)d_in[1];
  const float* fsin   = (const float*)d_in[2];
  const float* w_qkv  = (const float*)d_in[3];
  const float* w_proj = (const float*)d_in[4];
  const float* b_proj = (const float*)d_in[5];
  const float* g1     = (const float*)d_in[6];
  const float* beta1  = (const float*)d_in[7];
  const float* g2     = (const float*)d_in[8];
  const float* beta2  = (const float*)d_in[9];
  const float* w_fc1  = (const float*)d_in[10];
  const float* b_fc1  = (const float*)d_in[11];
  const float* w_fc2  = (const float*)d_in[12];
  const float* b_fc2  = (const float*)d_in[13];

  char* ws = (char*)d_ws;
  size_t off = 0;
  auto alloc = [&](size_t bytes) -> char* {
    char* p = ws + off; off += (bytes + 255) & ~(size_t)255; return p;
  };
  ushort* wq  = (ushort*)alloc((size_t)2304 * 768 * 2);
  ushort* wp  = (ushort*)alloc((size_t)768 * 768 * 2);
  ushort* w1  = (ushort*)alloc((size_t)3072 * 768 * 2);
  ushort* w2  = (ushort*)alloc((size_t)768 * 3072 * 2);
  ushort* h1  = (ushort*)alloc((size_t)4096 * 768 * 2);
  ushort* Qs  = (ushort*)alloc((size_t)12 * 4096 * 64 * 2);
  ushort* Ks  = (ushort*)alloc((size_t)12 * 4096 * 64 * 2);
  ushort* Vt  = (ushort*)alloc((size_t)12 * 64 * 4096 * 2);
  ushort* ao  = (ushort*)alloc((size_t)4096 * 768 * 2);
  ushort* x2b = (ushort*)alloc((size_t)4096 * 768 * 2);   // bf16 residual stream
  ushort* h2  = (ushort*)alloc((size_t)4096 * 768 * 2);
  ushort* f1  = (ushort*)alloc((size_t)4096 * 3072 * 2);
  float*  Opart = (float*)alloc((size_t)2 * 12 * 4096 * 64 * 4);   // 25MB (split-2)
  float*  Ml    = (float*)alloc((size_t)2 * 12 * 4096 * 2 * 4);
  ushort* skp16 = (ushort*)Opart;   // alias: fc2 bf16 partials (24MB) fit in Opart (25MB)

  // weights -> bf16 (one kernel)
  const int c0 = 2304*768/4, c1 = 768*768/4, c2 = 3072*768/4, c3 = 768*3072/4;
  cvt_all<<<(c0 + c1 + c2 + c3 + 255)/256, 256, 0, stream>>>(
      w_qkv, wq, c0, w_proj, wp, c1, w_fc1, w1, c2, w_fc2, w2, c3);

  // LN1 (wave-per-row, fp32 in)
  ln_kernel<float><<<1024, 256, 0, stream>>>(x, g1, beta1, h1);
  // QKV GEMM with fused RoPE + per-head scatter (MODE 4)
  gemm_bf16<4><<<dim3(32, 18), 256, 0, stream>>>(h1, 768, wq, 768, 768,
                                                 nullptr, nullptr, 0, nullptr, 0,
                                                 fcos, fsin, Qs, Ks, Vt);
  // attention (split-K over 2 segments) + combine
  flash_attn<<<dim3(32, 12, 2), 256, 0, stream>>>(Qs, Ks, Vt, Opart, Ml);
  attn_combine<<<4096, 192, 0, stream>>>(Opart, Ml, ao);
  // proj + residual -> bf16 residual stream: x2b = bf16(x + ao @ w_proj^T + b_proj)  (MODE 6)
  gemm_bf16<6><<<dim3(32, 6), 256, 0, stream>>>(ao, 768, wp, 768, 768,
                                                b_proj, x, 768, x2b, 768,
                                                nullptr, nullptr, nullptr, nullptr, nullptr);
  // LN2 (bf16 in)
  ln_kernel<ushort><<<1024, 256, 0, stream>>>(x2b, g2, beta2, h2);
  // fc1 + fast GELU: f1 = gelu(h2 @ w_fc1^T + b_fc1)  (bf16)
  gemm_bf16<2><<<dim3(32, 24), 256, 0, stream>>>(h2, 768, w1, 768, 768,
                                                 b_fc1, nullptr, 0, f1, 3072,
                                                 nullptr, nullptr, nullptr, nullptr, nullptr);
  // fc2 split-K=4 with BF16 partials (MODE 5), then combine + bias + bf16 residual -> fp32 out
  gemm_bf16<5><<<dim3(32, 6, 4), 256, 0, stream>>>(f1, 3072, w2, 3072, 768,
                                                   nullptr, nullptr, 0, skp16, 768,
                                                   nullptr, nullptr, nullptr, nullptr, nullptr);
  gemm_combine4_bf16<<<4096, 192, 0, stream>>>(skp16, b_fc2, x2b, (float*)d_out);
}

// Round 17
// 231.253 us; speedup vs baseline: 1.0002x; 1.0002x over previous
//
#include <hip/hip_runtime.h>
#include <hip/hip_bf16.h>
#include <math.h>

// Problem constants: B=1, N=4096, C=768, H=12, HD=64
#define LOG2E 1.44269504088896340736f

typedef short bf16x8 __attribute__((ext_vector_type(8)));
typedef float f32x4 __attribute__((ext_vector_type(4)));

static __device__ __forceinline__ float bf2f(ushort u){
  union { float f; unsigned int u; } x; x.u = ((unsigned int)u) << 16; return x.f;
}
static __device__ __forceinline__ ushort f2bf(float f){
  union { float f; unsigned int u; } x; x.f = f;
  unsigned int r = x.u + 0x7fffu + ((x.u >> 16) & 1u);   // RNE
  return (ushort)(r >> 16);
}
static __device__ __forceinline__ unsigned cvt_pk_bf16(float a, float b){
  unsigned r;
  asm("v_cvt_pk_bf16_f32 %0, %1, %2" : "=v"(r) : "v"(a), "v"(b));
  return r;   // lo = bf16(a), hi = bf16(b)
}
static __device__ __forceinline__ float fmax3(float a, float b, float c){
  return fmaxf(fmaxf(a, b), c);   // clang fuses to v_max3_f32
}
// tanh-form GELU, clamped so exp2 arg is bounded (provably finite for ALL inputs).
static __device__ __forceinline__ float gelu_fast(float v){
  float u = v + 0.044715f * v * v * v;
  u = fminf(u, 30.0f);
  float e = exp2f(2.3021187f * u);
  float inv = 1.0f / (e + 1.0f);
  return v - v * inv;
}
// lane <-> lane^1 exchange via DPP quad_perm [1,0,3,2] — pure VALU, no LDS
static __device__ __forceinline__ float dpp_xor1(float v){
  int i = __builtin_amdgcn_mov_dpp(__float_as_int(v), 0xB1, 0xF, 0xF, true);
  return __int_as_float(i);
}
// async global->LDS, 16B per lane; LDS dest = wave-uniform base + lane*16
static __device__ __forceinline__ void gload_lds16(const void* g, void* l){
  __builtin_amdgcn_global_load_lds(
      (const __attribute__((address_space(1))) unsigned int*)g,
      (__attribute__((address_space(3))) unsigned int*)l, 16, 0, 0);
}

// ---------------- fp32 -> bf16 weight conversion (all 4 weights, one kernel) ----------------
__global__ __launch_bounds__(256) void cvt_all(const float* __restrict__ s0, ushort* __restrict__ d0, int c0,
                                               const float* __restrict__ s1, ushort* __restrict__ d1, int c1,
                                               const float* __restrict__ s2, ushort* __restrict__ d2, int c2,
                                               const float* __restrict__ s3, ushort* __restrict__ d3, int c3){
  int j = blockIdx.x * 256 + threadIdx.x;
  const float* s; ushort* d;
  if (j < c0){ s = s0; d = d0; }
  else { j -= c0;
    if (j < c1){ s = s1; d = d1; }
    else { j -= c1;
      if (j < c2){ s = s2; d = d2; }
      else { j -= c2; if (j >= c3) return; s = s3; d = d3; } } }
  float4 v = ((const float4*)s)[j];
  ushort4 o;
  o.x = f2bf(v.x); o.y = f2bf(v.y); o.z = f2bf(v.z); o.w = f2bf(v.w);
  ((ushort4*)d)[j] = o;
}

// ---------------- LayerNorm (fp32 OR bf16 in -> bf16 out), one WAVE per row of 768 ----------------
template<typename T>
__global__ __launch_bounds__(256) void ln_kernel(const T* __restrict__ x,
                                                 const float* __restrict__ g,
                                                 const float* __restrict__ bta,
                                                 ushort* __restrict__ out){
  int w = threadIdx.x >> 6, l = threadIdx.x & 63;
  int row = blockIdx.x * 4 + w;
  const T* xr = x + (size_t)row * 768;
  f32x4 v[3];
  #pragma unroll
  for (int i = 0; i < 3; ++i){
    if constexpr (sizeof(T) == 4){
      v[i] = *(const f32x4*)(xr + i * 256 + l * 4);
    } else {
      ushort4 u = *(const ushort4*)(xr + i * 256 + l * 4);
      v[i][0] = bf2f(u.x); v[i][1] = bf2f(u.y); v[i][2] = bf2f(u.z); v[i][3] = bf2f(u.w);
    }
  }
  float s = 0.0f;
  #pragma unroll
  for (int i = 0; i < 3; ++i)
    #pragma unroll
    for (int r = 0; r < 4; ++r) s += v[i][r];
  #pragma unroll
  for (int off = 32; off; off >>= 1) s += __shfl_xor(s, off, 64);
  float mu = s * (1.0f / 768.0f);
  float q = 0.0f;
  #pragma unroll
  for (int i = 0; i < 3; ++i)
    #pragma unroll
    for (int r = 0; r < 4; ++r){ float d = v[i][r] - mu; q += d * d; }
  #pragma unroll
  for (int off = 32; off; off >>= 1) q += __shfl_xor(q, off, 64);
  float rs = rsqrtf(q * (1.0f / 768.0f) + 1e-5f);
  ushort* orow = out + (size_t)row * 768;
  #pragma unroll
  for (int i = 0; i < 3; ++i){
    f32x4 gg = *(const f32x4*)(g + i * 256 + l * 4);
    f32x4 bb = *(const f32x4*)(bta + i * 256 + l * 4);
    ushort4 o;
    o.x = f2bf((v[i][0] - mu) * rs * gg[0] + bb[0]);
    o.y = f2bf((v[i][1] - mu) * rs * gg[1] + bb[1]);
    o.z = f2bf((v[i][2] - mu) * rs * gg[2] + bb[2]);
    o.w = f2bf((v[i][3] - mu) * rs * gg[3] + bb[3]);
    *(ushort4*)(orow + i * 256 + l * 4) = o;
  }
}

// ---------------- generic bf16 MFMA GEMM: C[M,N] = A[M,K(+koff)] * B[N,K(+koff)]^T ----------------
// 128x128 tile, BK=64, 4 waves (2x2), DOUBLE-BUFFERED raw-barrier pipeline (round-15 win):
// stage(k+1) before compute(k); explicit asm waitcnt AFTER compute; raw s_barrier (no auto drain).
// MODE 0: bf16(C). MODE 1: fp32(C+bias+res). MODE 2: bf16(gelu_fast(C+bias)).
// MODE 3: fp32 partial (split-K). MODE 4: fused RoPE + Q/K/Vt scatter. MODE 5: bf16 partial (split-K).
// MODE 6: bf16(C + bias + fp32 res)
template<int MODE>
__global__ __launch_bounds__(256) void gemm_bf16(const ushort* __restrict__ A, int lda,
                                                 const ushort* __restrict__ Bm, int ldb,
                                                 int K,
                                                 const float* __restrict__ bias,
                                                 const float* __restrict__ res, int ldr,
                                                 void* __restrict__ out, int ldo,
                                                 const float* __restrict__ fc,
                                                 const float* __restrict__ fs,
                                                 ushort* __restrict__ Qs,
                                                 ushort* __restrict__ Ks,
                                                 ushort* __restrict__ Vt){
  __shared__ __align__(16) ushort As[2][128 * 64];
  __shared__ __align__(16) ushort Bs[2][128 * 64];
  const int tid = threadIdx.x;
  const int m0 = blockIdx.x * 128, n0 = blockIdx.y * 128;
  const int w = tid >> 6, l = tid & 63;
  const int wm = (w >> 1) * 64, wn = (w & 1) * 64;
  const int lr = l & 15, lg = l >> 4;
  const int lane8 = l >> 3, sl = l & 7;
  const int koff = (MODE == 3 || MODE == 5) ? blockIdx.z * K : 0;

  f32x4 acc[4][4] = {};

  auto stage = [&](int k0, int b){
    #pragma unroll
    for (int j = 0; j < 4; ++j){
      int instr = w * 4 + j;               // 0..15, 1KB each
      int row = instr * 8 + lane8;         // 0..127
      gload_lds16((const char*)A + ((size_t)(m0 + row) * lda + koff + k0) * 2 + ((sl ^ (row & 7)) << 4),
                  (char*)&As[b][0] + instr * 1024);
      gload_lds16((const char*)Bm + ((size_t)(n0 + row) * ldb + koff + k0) * 2 + ((sl ^ (row & 7)) << 4),
                  (char*)&Bs[b][0] + instr * 1024);
    }
  };

  const int nk = K >> 6;
  stage(0, 0);
  asm volatile("s_waitcnt vmcnt(0)" ::: "memory");
  __builtin_amdgcn_s_barrier();

  #pragma unroll 1
  for (int ki = 0; ki < nk; ++ki){
    const int b = ki & 1;
    if (ki + 1 < nk) stage((ki + 1) << 6, b ^ 1);
    #pragma unroll
    for (int kk = 0; kk < 2; ++kk){
      bf16x8 af[4], bfr[4];
      #pragma unroll
      for (int mi = 0; mi < 4; ++mi){
        int row = wm + mi * 16 + lr;
        int cg = (kk * 4 + lg) ^ (row & 7);
        af[mi] = *(const bf16x8*)(&As[b][0] + row * 64 + cg * 8);
      }
      #pragma unroll
      for (int nj = 0; nj < 4; ++nj){
        int row = wn + nj * 16 + lr;
        int cg = (kk * 4 + lg) ^ (row & 7);
        bfr[nj] = *(const bf16x8*)(&Bs[b][0] + row * 64 + cg * 8);
      }
      #pragma unroll
      for (int mi = 0; mi < 4; ++mi)
        #pragma unroll
        for (int nj = 0; nj < 4; ++nj)
          acc[mi][nj] = __builtin_amdgcn_mfma_f32_16x16x32_bf16(af[mi], bfr[nj], acc[mi][nj], 0, 0, 0);
    }
    asm volatile("s_waitcnt vmcnt(0) lgkmcnt(0)" ::: "memory");
    __builtin_amdgcn_s_barrier();
  }

  const size_t zout = (MODE == 3 || MODE == 5) ? (size_t)blockIdx.z * gridDim.x * 128 * ldo : 0;

  if (MODE == 4){
    // fused RoPE + QKV scatter. col = n0+wn+nj*16+lr in [0,2304); part uniform per block
    const int part = n0 / 768;                    // 0=q, 1=k, 2=v
    const float qsc = 0.125f * LOG2E;
    #pragma unroll
    for (int mi = 0; mi < 4; ++mi){
      const int n_base = m0 + wm + mi * 16 + lg * 4;
      #pragma unroll
      for (int nj = 0; nj < 4; ++nj){
        const int col = n0 + wn + nj * 16 + lr;
        const int head = (col - part * 768) >> 6;
        const int d = col & 63;
        if (part == 2){
          ushort4 pk;
          pk.x = f2bf(acc[mi][nj][0]); pk.y = f2bf(acc[mi][nj][1]);
          pk.z = f2bf(acc[mi][nj][2]); pk.w = f2bf(acc[mi][nj][3]);
          *(ushort4*)(Vt + ((size_t)head * 64 + d) * 4096 + n_base) = pk;
        } else {
          const int p = d >> 1;
          ushort* dst = (part == 0) ? Qs : Ks;
          #pragma unroll
          for (int r = 0; r < 4; ++r){
            int n = n_base + r;
            float v = acc[mi][nj][r];
            float pv = dpp_xor1(v);               // partner element (col^1)
            float c = fc[(size_t)n * 32 + p];
            float sv = fs[(size_t)n * 32 + p];
            float rr = v * c + pv * ((d & 1) ? sv : -sv);
            if (part == 0) rr *= qsc;
            dst[((size_t)head * 4096 + n) * 64 + d] = f2bf(rr);
          }
        }
      }
    }
    return;
  }

  // epilogue: D layout row=(lane>>4)*4+reg, col=lane&15 (m89-verified)
  #pragma unroll
  for (int mi = 0; mi < 4; ++mi){
    #pragma unroll
    for (int nj = 0; nj < 4; ++nj){
      #pragma unroll
      for (int r = 0; r < 4; ++r){
        int grow = m0 + wm + mi * 16 + lg * 4 + r;
        int gcol = n0 + wn + nj * 16 + lr;
        float v = acc[mi][nj][r];
        if (MODE == 0){
          ((ushort*)out)[(size_t)grow * ldo + gcol] = f2bf(v);
        } else if (MODE == 1){
          v += bias[gcol] + res[(size_t)grow * ldr + gcol];
          ((float*)out)[(size_t)grow * ldo + gcol] = v;
        } else if (MODE == 2){
          v = gelu_fast(v + bias[gcol]);
          ((ushort*)out)[(size_t)grow * ldo + gcol] = f2bf(v);
        } else if (MODE == 3){
          ((float*)out)[zout + (size_t)grow * ldo + gcol] = v;
        } else if (MODE == 5){
          ((ushort*)out)[zout + (size_t)grow * ldo + gcol] = f2bf(v);
        } else {
          v += bias[gcol] + res[(size_t)grow * ldr + gcol];
          ((ushort*)out)[(size_t)grow * ldo + gcol] = f2bf(v);
        }
      }
    }
  }
}

// ---------------- split-K=4 GEMM combine (bf16 partials + bf16 residual): out fp32 ----------------
__global__ __launch_bounds__(192) void gemm_combine4_bf16(const ushort* __restrict__ parts,
                                                          const float* __restrict__ bias,
                                                          const ushort* __restrict__ res,
                                                          float* __restrict__ out){
  int q = blockIdx.x, t = threadIdx.x;
  size_t idx = (size_t)q * 768 + t * 4;
  const size_t seg = (size_t)4096 * 768;
  f32x4 o = {};
  #pragma unroll
  for (int s = 0; s < 4; ++s){
    ushort4 p = *(const ushort4*)(parts + s * seg + idx);
    o[0] += bf2f(p.x); o[1] += bf2f(p.y); o[2] += bf2f(p.z); o[3] += bf2f(p.w);
  }
  f32x4 b = *(const f32x4*)(bias + t * 4);
  ushort4 rr4 = *(const ushort4*)(res + idx);
  o[0] += b[0] + bf2f(rr4.x);
  o[1] += b[1] + bf2f(rr4.y);
  o[2] += b[2] + bf2f(rr4.z);
  o[3] += b[3] + bf2f(rr4.w);
  *(f32x4*)(out + idx) = o;
}

// ---------------- flash attention, split-K=2: grid (32, 12, 2), 4 waves x 32 q-rows ----------------
// QK^T C pre-initialized to -m_prev (defer-max); __all(lane_max <= 8) defer check (no shuffles);
// row-sum via mfma(ones, P); fp32 O partials (25MB, half of split-4); s_setprio around MFMA.
__global__ __launch_bounds__(256, 4) void flash_attn(const ushort* __restrict__ Qs,
                                                     const ushort* __restrict__ Ks,
                                                     const ushort* __restrict__ Vt,
                                                     float* __restrict__ Opart,
                                                     float* __restrict__ Ml){
  __shared__ __align__(16) char smem[32768];   // 2 bufs x (K 8KB + V 8KB)
  const int h = blockIdx.y, kh = blockIdx.z;
  const int w = threadIdx.x >> 6, l = threadIdx.x & 63;
  const int lr = l & 15, lg = l >> 4;
  const int lane8 = l >> 3, sl = l & 7;
  const int q0 = blockIdx.x * 128 + w * 32;
  const ushort* Qh = Qs + (size_t)h * (4096 * 64);
  const char* Kh = (const char*)(Ks + (size_t)h * (4096 * 64));
  const char* Vh = (const char*)(Vt + (size_t)h * (64 * 4096));

  bf16x8 qa[2][2];
  #pragma unroll
  for (int qf = 0; qf < 2; ++qf)
    #pragma unroll
    for (int kk = 0; kk < 2; ++kk)
      qa[qf][kk] = *(const bf16x8*)(Qh + (size_t)(q0 + qf * 16 + lr) * 64 + kk * 32 + lg * 8);

  // staging bases (inverse-swizzled source, T21); kh selects the 2048-key segment
  const char* kbase = Kh + (size_t)(kh * 2048 + w * 16 + lane8) * 128;
  const char* vbase = Vh + (size_t)(w * 16 + lane8) * 8192 + kh * 4096 + ((sl ^ lane8) << 4);
  int koff[2];
  #pragma unroll
  for (int j = 0; j < 2; ++j)
    koff[j] = j * 1024 + ((sl ^ ((lane8 & 3) | (((w * 2 + j) & 1) << 2))) << 4);

  // LDS read offsets (hoisted; K swizzle slot is t-independent)
  const int a_ = lr >> 2, b_ = lr & 3;
  const int krow = 8 * a_ + b_;                 // permuted K-row base
  const int f_ = b_ | ((a_ & 1) << 2);
  const int kslot0 = (lg ^ f_) << 4;
  const int kslot1 = ((4 + lg) ^ f_) << 4;
  const int vslot0 = lr * 128 + ((lg ^ (lr & 7)) << 4);
  const int vslot1 = lr * 128 + (((4 + lg) ^ (lr & 7)) << 4);

  f32x4 oacc[2][4] = {};        // C[d = db*16 + 4lg + r][q = lr] per qf
  f32x4 lacc[2] = {};           // row-sum accumulator
  float m_prev[2] = {0.0f, 0.0f};
  union { unsigned u[4]; bf16x8 v; } ones;
  #pragma unroll
  for (int i = 0; i < 4; ++i) ones.u[i] = 0x3F803F80u;

  auto stage = [&](int tile, char* Kb, char* Vb){
    #pragma unroll
    for (int j = 0; j < 2; ++j){
      gload_lds16(kbase + (size_t)tile * 8192 + koff[j], Kb + (w * 2 + j) * 1024);
      gload_lds16(vbase + (size_t)j * 65536 + (size_t)tile * 128, Vb + (w * 2 + j) * 1024);
    }
  };

  auto compute = [&](const char* Kb, const char* Vb, bool first){
    f32x4 sh[2][4];
    #pragma unroll
    for (int qf = 0; qf < 2; ++qf){
      float iv = first ? 0.0f : -m_prev[qf];
      #pragma unroll
      for (int t = 0; t < 4; ++t){
        sh[qf][t][0] = iv; sh[qf][t][1] = iv; sh[qf][t][2] = iv; sh[qf][t][3] = iv;
      }
    }
    __builtin_amdgcn_s_setprio(1);
    #pragma unroll
    for (int t = 0; t < 4; ++t){
      const char* kr = Kb + (krow + 4 * (t & 1) + 32 * (t >> 1)) * 128;
      bf16x8 k0 = *(const bf16x8*)(kr + kslot0);
      bf16x8 k1 = *(const bf16x8*)(kr + kslot1);
      #pragma unroll
      for (int qf = 0; qf < 2; ++qf){
        sh[qf][t] = __builtin_amdgcn_mfma_f32_16x16x32_bf16(k0, qa[qf][0], sh[qf][t], 0, 0, 0);
        sh[qf][t] = __builtin_amdgcn_mfma_f32_16x16x32_bf16(k1, qa[qf][1], sh[qf][t], 0, 0, 0);
      }
    }
    __builtin_amdgcn_s_setprio(0);
    // lane-local max per qf (16 values, 7 max ops) — no shuffles
    float mb[2];
    #pragma unroll
    for (int qf = 0; qf < 2; ++qf){
      float m1 = fmax3(sh[qf][0][0], sh[qf][0][1], sh[qf][0][2]);
      float m2 = fmax3(sh[qf][0][3], sh[qf][1][0], sh[qf][1][1]);
      float m3 = fmax3(sh[qf][1][2], sh[qf][1][3], sh[qf][2][0]);
      float m4 = fmax3(sh[qf][2][1], sh[qf][2][2], sh[qf][2][3]);
      float m5 = fmax3(sh[qf][3][0], sh[qf][3][1], sh[qf][3][2]);
      mb[qf] = fmax3(fmaxf(m1, m2), fmax3(m3, m4, m5), sh[qf][3][3]);
    }
    if (first){
      #pragma unroll
      for (int qf = 0; qf < 2; ++qf){
        float mm = fmaxf(mb[qf], __shfl_xor(mb[qf], 16, 64));
        mm = fmaxf(mm, __shfl_xor(mm, 32, 64));
        m_prev[qf] = mm;
        #pragma unroll
        for (int t = 0; t < 4; ++t)
          #pragma unroll
          for (int r = 0; r < 4; ++r) sh[qf][t][r] -= mm;
      }
    } else if (!__all(mb[0] <= 8.0f && mb[1] <= 8.0f)){
      #pragma unroll
      for (int qf = 0; qf < 2; ++qf){
        float mm = fmaxf(mb[qf], __shfl_xor(mb[qf], 16, 64));
        mm = fmaxf(mm, __shfl_xor(mm, 32, 64));
        float d = (mm > 8.0f) ? mm : 0.0f;       // sh already = S - m_prev
        float sc = exp2f(-d);
        #pragma unroll
        for (int t = 0; t < 4; ++t)
          #pragma unroll
          for (int r = 0; r < 4; ++r) sh[qf][t][r] -= d;
        #pragma unroll
        for (int db = 0; db < 4; ++db)
          #pragma unroll
          for (int r = 0; r < 4; ++r) oacc[qf][db][r] *= sc;
        #pragma unroll
        for (int r = 0; r < 4; ++r) lacc[qf][r] *= sc;
        m_prev[qf] += d;
      }
    }
    #pragma unroll
    for (int qf = 0; qf < 2; ++qf)
      #pragma unroll
      for (int t = 0; t < 4; ++t)
        #pragma unroll
        for (int r = 0; r < 4; ++r)
          sh[qf][t][r] = exp2f(sh[qf][t][r]);     // Q pre-scaled by log2e
    #pragma unroll
    for (int kk = 0; kk < 2; ++kk){
      union { unsigned u[4]; bf16x8 v; } pf[2];
      #pragma unroll
      for (int qf = 0; qf < 2; ++qf){
        pf[qf].u[0] = cvt_pk_bf16(sh[qf][2*kk][0],   sh[qf][2*kk][1]);
        pf[qf].u[1] = cvt_pk_bf16(sh[qf][2*kk][2],   sh[qf][2*kk][3]);
        pf[qf].u[2] = cvt_pk_bf16(sh[qf][2*kk+1][0], sh[qf][2*kk+1][1]);
        pf[qf].u[3] = cvt_pk_bf16(sh[qf][2*kk+1][2], sh[qf][2*kk+1][3]);
      }
      const int vs = kk ? vslot1 : vslot0;
      __builtin_amdgcn_s_setprio(1);
      #pragma unroll
      for (int db = 0; db < 4; ++db){
        bf16x8 vf = *(const bf16x8*)(Vb + vs + db * 2048);
        #pragma unroll
        for (int qf = 0; qf < 2; ++qf)
          oacc[qf][db] = __builtin_amdgcn_mfma_f32_16x16x32_bf16(vf, pf[qf].v, oacc[qf][db], 0, 0, 0);
      }
      #pragma unroll
      for (int qf = 0; qf < 2; ++qf)
        lacc[qf] = __builtin_amdgcn_mfma_f32_16x16x32_bf16(ones.v, pf[qf].v, lacc[qf], 0, 0, 0);
      __builtin_amdgcn_s_setprio(0);
    }
  };

  char* K0 = smem;          char* V0 = smem + 8192;
  char* K1 = smem + 16384;  char* V1 = smem + 24576;

  stage(0, K0, V0);
  __syncthreads();
  stage(1, K1, V1);
  compute(K0, V0, true);
  __syncthreads();
  stage(2, K0, V0);
  compute(K1, V1, false);
  __syncthreads();
  #pragma unroll 1
  for (int it2 = 1; it2 < 16; ++it2){            // 32 tiles = 2048 keys per segment
    stage(2 * it2 + 1, K1, V1);
    compute(K0, V0, false);
    __syncthreads();
    if (it2 < 15) stage(2 * it2 + 2, K0, V0);
    compute(K1, V1, false);
    __syncthreads();
  }

  #pragma unroll
  for (int qf = 0; qf < 2; ++qf){
    int q = q0 + qf * 16 + lr;
    float* Op = Opart + ((size_t)(kh * 12 + h) * 4096 + q) * 64;
    #pragma unroll
    for (int db = 0; db < 4; ++db)
      *(f32x4*)(Op + db * 16 + 4 * lg) = oacc[qf][db];
    if (lg == 0){
      float2 ml; ml.x = m_prev[qf]; ml.y = lacc[qf][0];
      *(float2*)(Ml + ((size_t)(kh * 12 + h) * 4096 + q) * 2) = ml;
    }
  }
}

// ---------------- split-K=2 attention combine (fp32 partials) ----------------
__global__ __launch_bounds__(192) void attn_combine(const float* __restrict__ Opart,
                                                    const float* __restrict__ Ml,
                                                    ushort* __restrict__ O){
  int q = blockIdx.x, t = threadIdx.x;           // t in [0,192): h = t>>4, d = (t&15)*4
  int h = t >> 4;
  float2 ml[2];
  #pragma unroll
  for (int s = 0; s < 2; ++s)
    ml[s] = *(const float2*)(Ml + ((size_t)(s * 12 + h) * 4096 + q) * 2);
  float m = fmaxf(ml[0].x, ml[1].x);
  float w0 = exp2f(ml[0].x - m), w1 = exp2f(ml[1].x - m);
  float inv = 1.0f / (ml[0].y * w0 + ml[1].y * w1);
  int dd = (t & 15) * 4;
  f32x4 o0 = *(const f32x4*)(Opart + ((size_t)h * 4096 + q) * 64 + dd);
  f32x4 o1 = *(const f32x4*)(Opart + ((size_t)(12 + h) * 4096 + q) * 64 + dd);
  uint2 ov;
  ov.x = cvt_pk_bf16((o0[0]*w0 + o1[0]*w1) * inv, (o0[1]*w0 + o1[1]*w1) * inv);
  ov.y = cvt_pk_bf16((o0[2]*w0 + o1[2]*w1) * inv, (o0[3]*w0 + o1[3]*w1) * inv);
  *(uint2*)(O + (size_t)q * 768 + t * 4) = ov;
}

// ---------------- launch ----------------
extern "C" void kernel_launch(void* const* d_in, const int* in_sizes, int n_in,
                              void* d_out, int out_size, void* d_ws, size_t ws_size,
                              hipStream_t stream){
  const float* x      = (const float*)d_in[0];
  const float* fcos   = (const float*)d_in[1];
  const float* fsin   = (const float*)d_in[2];
  const float* w_qkv  = (const float*)d_in[3];
  const float* w_proj = (const float*)d_in[4];
  const float* b_proj = (const float*)d_in[5];
  const float* g1     = (const float*)d_in[6];
  const float* beta1  = (const float*)d_in[7];
  const float* g2     = (const float*)d_in[8];
  const float* beta2  = (const float*)d_in[9];
  const float* w_fc1  = (const float*)d_in[10];
  const float* b_fc1  = (const float*)d_in[11];
  const float* w_fc2  = (const float*)d_in[12];
  const float* b_fc2  = (const float*)d_in[13];

  char* ws = (char*)d_ws;
  size_t off = 0;
  auto alloc = [&](size_t bytes) -> char* {
    char* p = ws + off; off += (bytes + 255) & ~(size_t)255; return p;
  };
  ushort* wq  = (ushort*)alloc((size_t)2304 * 768 * 2);
  ushort* wp  = (ushort*)alloc((size_t)768 * 768 * 2);
  ushort* w1  = (ushort*)alloc((size_t)3072 * 768 * 2);
  ushort* w2  = (ushort*)alloc((size_t)768 * 3072 * 2);
  ushort* h1  = (ushort*)alloc((size_t)4096 * 768 * 2);
  ushort* Qs  = (ushort*)alloc((size_t)12 * 4096 * 64 * 2);
  ushort* Ks  = (ushort*)alloc((size_t)12 * 4096 * 64 * 2);
  ushort* Vt  = (ushort*)alloc((size_t)12 * 64 * 4096 * 2);
  ushort* ao  = (ushort*)alloc((size_t)4096 * 768 * 2);
  ushort* x2b = (ushort*)alloc((size_t)4096 * 768 * 2);   // bf16 residual stream
  ushort* h2  = (ushort*)alloc((size_t)4096 * 768 * 2);
  ushort* f1  = (ushort*)alloc((size_t)4096 * 3072 * 2);
  float*  Opart = (float*)alloc((size_t)2 * 12 * 4096 * 64 * 4);   // 25MB (split-2)
  float*  Ml    = (float*)alloc((size_t)2 * 12 * 4096 * 2 * 4);
  ushort* skp16 = (ushort*)Opart;   // alias: fc2 bf16 partials (24MB) fit in Opart (25MB)

  // weights -> bf16 (one kernel)
  const int c0 = 2304*768/4, c1 = 768*768/4, c2 = 3072*768/4, c3 = 768*3072/4;
  cvt_all<<<(c0 + c1 + c2 + c3 + 255)/256, 256, 0, stream>>>(
      w_qkv, wq, c0, w_proj, wp, c1, w_fc1, w1, c2, w_fc2, w2, c3);

  // LN1 (wave-per-row, fp32 in)
  ln_kernel<float><<<1024, 256, 0, stream>>>(x, g1, beta1, h1);
  // QKV GEMM with fused RoPE + per-head scatter (MODE 4)
  gemm_bf16<4><<<dim3(32, 18), 256, 0, stream>>>(h1, 768, wq, 768, 768,
                                                 nullptr, nullptr, 0, nullptr, 0,
                                                 fcos, fsin, Qs, Ks, Vt);
  // attention (split-K over 2 segments) + combine
  flash_attn<<<dim3(32, 12, 2), 256, 0, stream>>>(Qs, Ks, Vt, Opart, Ml);
  attn_combine<<<4096, 192, 0, stream>>>(Opart, Ml, ao);
  // proj + residual -> bf16 residual stream: x2b = bf16(x + ao @ w_proj^T + b_proj)  (MODE 6)
  gemm_bf16<6><<<dim3(32, 6), 256, 0, stream>>>(ao, 768, wp, 768, 768,
                                                b_proj, x, 768, x2b, 768,
                                                nullptr, nullptr, nullptr, nullptr, nullptr);
  // LN2 (bf16 in)
  ln_kernel<ushort><<<1024, 256, 0, stream>>>(x2b, g2, beta2, h2);
  // fc1 + fast GELU: f1 = gelu(h2 @ w_fc1^T + b_fc1)  (bf16)
  gemm_bf16<2><<<dim3(32, 24), 256, 0, stream>>>(h2, 768, w1, 768, 768,
                                                 b_fc1, nullptr, 0, f1, 3072,
                                                 nullptr, nullptr, nullptr, nullptr, nullptr);
  // fc2 split-K=4 with BF16 partials (MODE 5), then combine + bias + bf16 residual -> fp32 out
  gemm_bf16<5><<<dim3(32, 6, 4), 256, 0, stream>>>(f1, 3072, w2, 3072, 768,
                                                   nullptr, nullptr, 0, skp16, 768,
                                                   nullptr, nullptr, nullptr, nullptr, nullptr);
  gemm_combine4_bf16<<<4096, 192, 0, stream>>>(skp16, b_fc2, x2b, (float*)d_out);
}

// Round 18
// 229.178 us; speedup vs baseline: 1.0092x; 1.0091x over previous
//
#include <hip/hip_runtime.h>
#include <hip/hip_bf16.h>
#include <math.h>

// Problem constants: B=1, N=4096, C=768, H=12, HD=64
#define LOG2E 1.44269504088896340736f

typedef short bf16x8 __attribute__((ext_vector_type(8)));
typedef float f32x4 __attribute__((ext_vector_type(4)));

static __device__ __forceinline__ float bf2f(ushort u){
  union { float f; unsigned int u; } x; x.u = ((unsigned int)u) << 16; return x.f;
}
static __device__ __forceinline__ ushort f2bf(float f){
  union { float f; unsigned int u; } x; x.f = f;
  unsigned int r = x.u + 0x7fffu + ((x.u >> 16) & 1u);   // RNE
  return (ushort)(r >> 16);
}
static __device__ __forceinline__ unsigned cvt_pk_bf16(float a, float b){
  unsigned r;
  asm("v_cvt_pk_bf16_f32 %0, %1, %2" : "=v"(r) : "v"(a), "v"(b));
  return r;   // lo = bf16(a), hi = bf16(b)
}
static __device__ __forceinline__ float fmax3(float a, float b, float c){
  return fmaxf(fmaxf(a, b), c);   // clang fuses to v_max3_f32
}
// tanh-form GELU, clamped so exp2 arg is bounded (provably finite for ALL inputs).
static __device__ __forceinline__ float gelu_fast(float v){
  float u = v + 0.044715f * v * v * v;
  u = fminf(u, 30.0f);
  float e = exp2f(2.3021187f * u);
  float inv = 1.0f / (e + 1.0f);
  return v - v * inv;
}
// lane <-> lane^1 exchange via DPP quad_perm [1,0,3,2] — pure VALU, no LDS
static __device__ __forceinline__ float dpp_xor1(float v){
  int i = __builtin_amdgcn_mov_dpp(__float_as_int(v), 0xB1, 0xF, 0xF, true);
  return __int_as_float(i);
}
// async global->LDS, 16B per lane; LDS dest = wave-uniform base + lane*16
static __device__ __forceinline__ void gload_lds16(const void* g, void* l){
  __builtin_amdgcn_global_load_lds(
      (const __attribute__((address_space(1))) unsigned int*)g,
      (__attribute__((address_space(3))) unsigned int*)l, 16, 0, 0);
}

// ---------------- fused prep: blocks 0..1023 = LN1 (wave-per-row); blocks 1024+ = weight cvt ----------------
__global__ __launch_bounds__(256) void prep_kernel(const float* __restrict__ x,
                                                   const float* __restrict__ g,
                                                   const float* __restrict__ bta,
                                                   ushort* __restrict__ lnout,
                                                   const float* __restrict__ s0, ushort* __restrict__ d0, int c0,
                                                   const float* __restrict__ s1, ushort* __restrict__ d1, int c1,
                                                   const float* __restrict__ s2, ushort* __restrict__ d2, int c2,
                                                   const float* __restrict__ s3, ushort* __restrict__ d3, int c3){
  if (blockIdx.x < 1024){
    int w = threadIdx.x >> 6, l = threadIdx.x & 63;
    int row = blockIdx.x * 4 + w;
    const float* xr = x + (size_t)row * 768;
    f32x4 v[3];
    #pragma unroll
    for (int i = 0; i < 3; ++i) v[i] = *(const f32x4*)(xr + i * 256 + l * 4);
    float s = 0.0f;
    #pragma unroll
    for (int i = 0; i < 3; ++i)
      #pragma unroll
      for (int r = 0; r < 4; ++r) s += v[i][r];
    #pragma unroll
    for (int off = 32; off; off >>= 1) s += __shfl_xor(s, off, 64);
    float mu = s * (1.0f / 768.0f);
    float q = 0.0f;
    #pragma unroll
    for (int i = 0; i < 3; ++i)
      #pragma unroll
      for (int r = 0; r < 4; ++r){ float d = v[i][r] - mu; q += d * d; }
    #pragma unroll
    for (int off = 32; off; off >>= 1) q += __shfl_xor(q, off, 64);
    float rs = rsqrtf(q * (1.0f / 768.0f) + 1e-5f);
    ushort* orow = lnout + (size_t)row * 768;
    #pragma unroll
    for (int i = 0; i < 3; ++i){
      f32x4 gg = *(const f32x4*)(g + i * 256 + l * 4);
      f32x4 bb = *(const f32x4*)(bta + i * 256 + l * 4);
      ushort4 o;
      o.x = f2bf((v[i][0] - mu) * rs * gg[0] + bb[0]);
      o.y = f2bf((v[i][1] - mu) * rs * gg[1] + bb[1]);
      o.z = f2bf((v[i][2] - mu) * rs * gg[2] + bb[2]);
      o.w = f2bf((v[i][3] - mu) * rs * gg[3] + bb[3]);
      *(ushort4*)(orow + i * 256 + l * 4) = o;
    }
    return;
  }
  int j = (blockIdx.x - 1024) * 256 + threadIdx.x;
  const float* s; ushort* d;
  if (j < c0){ s = s0; d = d0; }
  else { j -= c0;
    if (j < c1){ s = s1; d = d1; }
    else { j -= c1;
      if (j < c2){ s = s2; d = d2; }
      else { j -= c2; if (j >= c3) return; s = s3; d = d3; } } }
  float4 v = ((const float4*)s)[j];
  ushort4 o;
  o.x = f2bf(v.x); o.y = f2bf(v.y); o.z = f2bf(v.z); o.w = f2bf(v.w);
  ((ushort4*)d)[j] = o;
}

// ---------------- LayerNorm (bf16 in -> bf16 out), one WAVE per row of 768 ----------------
__global__ __launch_bounds__(256) void ln_kernel_bf16(const ushort* __restrict__ x,
                                                      const float* __restrict__ g,
                                                      const float* __restrict__ bta,
                                                      ushort* __restrict__ out){
  int w = threadIdx.x >> 6, l = threadIdx.x & 63;
  int row = blockIdx.x * 4 + w;
  const ushort* xr = x + (size_t)row * 768;
  f32x4 v[3];
  #pragma unroll
  for (int i = 0; i < 3; ++i){
    ushort4 u = *(const ushort4*)(xr + i * 256 + l * 4);
    v[i][0] = bf2f(u.x); v[i][1] = bf2f(u.y); v[i][2] = bf2f(u.z); v[i][3] = bf2f(u.w);
  }
  float s = 0.0f;
  #pragma unroll
  for (int i = 0; i < 3; ++i)
    #pragma unroll
    for (int r = 0; r < 4; ++r) s += v[i][r];
  #pragma unroll
  for (int off = 32; off; off >>= 1) s += __shfl_xor(s, off, 64);
  float mu = s * (1.0f / 768.0f);
  float q = 0.0f;
  #pragma unroll
  for (int i = 0; i < 3; ++i)
    #pragma unroll
    for (int r = 0; r < 4; ++r){ float d = v[i][r] - mu; q += d * d; }
  #pragma unroll
  for (int off = 32; off; off >>= 1) q += __shfl_xor(q, off, 64);
  float rs = rsqrtf(q * (1.0f / 768.0f) + 1e-5f);
  ushort* orow = out + (size_t)row * 768;
  #pragma unroll
  for (int i = 0; i < 3; ++i){
    f32x4 gg = *(const f32x4*)(g + i * 256 + l * 4);
    f32x4 bb = *(const f32x4*)(bta + i * 256 + l * 4);
    ushort4 o;
    o.x = f2bf((v[i][0] - mu) * rs * gg[0] + bb[0]);
    o.y = f2bf((v[i][1] - mu) * rs * gg[1] + bb[1]);
    o.z = f2bf((v[i][2] - mu) * rs * gg[2] + bb[2]);
    o.w = f2bf((v[i][3] - mu) * rs * gg[3] + bb[3]);
    *(ushort4*)(orow + i * 256 + l * 4) = o;
  }
}

// ---------------- generic bf16 MFMA GEMM: C[M,N] = A[M,K(+koff)] * B[N,K(+koff)]^T ----------------
// 128x128 tile, BK=64, 4 waves (2x2), DOUBLE-BUFFERED raw-barrier pipeline (round-15 win):
// stage(k+1) before compute(k); explicit asm waitcnt AFTER compute; raw s_barrier (no auto drain).
// MODE 0: bf16(C). MODE 1: fp32(C+bias+res). MODE 2: bf16(gelu_fast(C+bias)).
// MODE 3: fp32 partial (split-K). MODE 4: fused RoPE + Q/K/Vt scatter. MODE 5: bf16 partial (split-K).
// MODE 6: bf16(C + bias + fp32 res)
template<int MODE>
__global__ __launch_bounds__(256) void gemm_bf16(const ushort* __restrict__ A, int lda,
                                                 const ushort* __restrict__ Bm, int ldb,
                                                 int K,
                                                 const float* __restrict__ bias,
                                                 const float* __restrict__ res, int ldr,
                                                 void* __restrict__ out, int ldo,
                                                 const float* __restrict__ fc,
                                                 const float* __restrict__ fs,
                                                 ushort* __restrict__ Qs,
                                                 ushort* __restrict__ Ks,
                                                 ushort* __restrict__ Vt){
  __shared__ __align__(16) ushort As[2][128 * 64];
  __shared__ __align__(16) ushort Bs[2][128 * 64];
  const int tid = threadIdx.x;
  const int m0 = blockIdx.x * 128, n0 = blockIdx.y * 128;
  const int w = tid >> 6, l = tid & 63;
  const int wm = (w >> 1) * 64, wn = (w & 1) * 64;
  const int lr = l & 15, lg = l >> 4;
  const int lane8 = l >> 3, sl = l & 7;
  const int koff = (MODE == 3 || MODE == 5) ? blockIdx.z * K : 0;

  f32x4 acc[4][4] = {};

  auto stage = [&](int k0, int b){
    #pragma unroll
    for (int j = 0; j < 4; ++j){
      int instr = w * 4 + j;               // 0..15, 1KB each
      int row = instr * 8 + lane8;         // 0..127
      gload_lds16((const char*)A + ((size_t)(m0 + row) * lda + koff + k0) * 2 + ((sl ^ (row & 7)) << 4),
                  (char*)&As[b][0] + instr * 1024);
      gload_lds16((const char*)Bm + ((size_t)(n0 + row) * ldb + koff + k0) * 2 + ((sl ^ (row & 7)) << 4),
                  (char*)&Bs[b][0] + instr * 1024);
    }
  };

  const int nk = K >> 6;
  stage(0, 0);
  asm volatile("s_waitcnt vmcnt(0)" ::: "memory");
  __builtin_amdgcn_s_barrier();

  #pragma unroll 1
  for (int ki = 0; ki < nk; ++ki){
    const int b = ki & 1;
    if (ki + 1 < nk) stage((ki + 1) << 6, b ^ 1);
    #pragma unroll
    for (int kk = 0; kk < 2; ++kk){
      bf16x8 af[4], bfr[4];
      #pragma unroll
      for (int mi = 0; mi < 4; ++mi){
        int row = wm + mi * 16 + lr;
        int cg = (kk * 4 + lg) ^ (row & 7);
        af[mi] = *(const bf16x8*)(&As[b][0] + row * 64 + cg * 8);
      }
      #pragma unroll
      for (int nj = 0; nj < 4; ++nj){
        int row = wn + nj * 16 + lr;
        int cg = (kk * 4 + lg) ^ (row & 7);
        bfr[nj] = *(const bf16x8*)(&Bs[b][0] + row * 64 + cg * 8);
      }
      #pragma unroll
      for (int mi = 0; mi < 4; ++mi)
        #pragma unroll
        for (int nj = 0; nj < 4; ++nj)
          acc[mi][nj] = __builtin_amdgcn_mfma_f32_16x16x32_bf16(af[mi], bfr[nj], acc[mi][nj], 0, 0, 0);
    }
    asm volatile("s_waitcnt vmcnt(0) lgkmcnt(0)" ::: "memory");
    __builtin_amdgcn_s_barrier();
  }

  const size_t zout = (MODE == 3 || MODE == 5) ? (size_t)blockIdx.z * gridDim.x * 128 * ldo : 0;

  if (MODE == 4){
    // fused RoPE + QKV scatter. col = n0+wn+nj*16+lr in [0,2304); part uniform per block
    const int part = n0 / 768;                    // 0=q, 1=k, 2=v
    const float qsc = 0.125f * LOG2E;
    #pragma unroll
    for (int mi = 0; mi < 4; ++mi){
      const int n_base = m0 + wm + mi * 16 + lg * 4;
      #pragma unroll
      for (int nj = 0; nj < 4; ++nj){
        const int col = n0 + wn + nj * 16 + lr;
        const int head = (col - part * 768) >> 6;
        const int d = col & 63;
        if (part == 2){
          ushort4 pk;
          pk.x = f2bf(acc[mi][nj][0]); pk.y = f2bf(acc[mi][nj][1]);
          pk.z = f2bf(acc[mi][nj][2]); pk.w = f2bf(acc[mi][nj][3]);
          *(ushort4*)(Vt + ((size_t)head * 64 + d) * 4096 + n_base) = pk;
        } else {
          const int p = d >> 1;
          ushort* dst = (part == 0) ? Qs : Ks;
          #pragma unroll
          for (int r = 0; r < 4; ++r){
            int n = n_base + r;
            float v = acc[mi][nj][r];
            float pv = dpp_xor1(v);               // partner element (col^1)
            float c = fc[(size_t)n * 32 + p];
            float sv = fs[(size_t)n * 32 + p];
            float rr = v * c + pv * ((d & 1) ? sv : -sv);
            if (part == 0) rr *= qsc;
            dst[((size_t)head * 4096 + n) * 64 + d] = f2bf(rr);
          }
        }
      }
    }
    return;
  }

  // epilogue: D layout row=(lane>>4)*4+reg, col=lane&15 (m89-verified)
  #pragma unroll
  for (int mi = 0; mi < 4; ++mi){
    #pragma unroll
    for (int nj = 0; nj < 4; ++nj){
      #pragma unroll
      for (int r = 0; r < 4; ++r){
        int grow = m0 + wm + mi * 16 + lg * 4 + r;
        int gcol = n0 + wn + nj * 16 + lr;
        float v = acc[mi][nj][r];
        if (MODE == 0){
          ((ushort*)out)[(size_t)grow * ldo + gcol] = f2bf(v);
        } else if (MODE == 1){
          v += bias[gcol] + res[(size_t)grow * ldr + gcol];
          ((float*)out)[(size_t)grow * ldo + gcol] = v;
        } else if (MODE == 2){
          v = gelu_fast(v + bias[gcol]);
          ((ushort*)out)[(size_t)grow * ldo + gcol] = f2bf(v);
        } else if (MODE == 3){
          ((float*)out)[zout + (size_t)grow * ldo + gcol] = v;
        } else if (MODE == 5){
          ((ushort*)out)[zout + (size_t)grow * ldo + gcol] = f2bf(v);
        } else {
          v += bias[gcol] + res[(size_t)grow * ldr + gcol];
          ((ushort*)out)[(size_t)grow * ldo + gcol] = f2bf(v);
        }
      }
    }
  }
}

// ---------------- split-K=4 GEMM combine (bf16 partials + bf16 residual): out fp32 ----------------
__global__ __launch_bounds__(192) void gemm_combine4_bf16(const ushort* __restrict__ parts,
                                                          const float* __restrict__ bias,
                                                          const ushort* __restrict__ res,
                                                          float* __restrict__ out){
  int q = blockIdx.x, t = threadIdx.x;
  size_t idx = (size_t)q * 768 + t * 4;
  const size_t seg = (size_t)4096 * 768;
  f32x4 o = {};
  #pragma unroll
  for (int s = 0; s < 4; ++s){
    ushort4 p = *(const ushort4*)(parts + s * seg + idx);
    o[0] += bf2f(p.x); o[1] += bf2f(p.y); o[2] += bf2f(p.z); o[3] += bf2f(p.w);
  }
  f32x4 b = *(const f32x4*)(bias + t * 4);
  ushort4 rr4 = *(const ushort4*)(res + idx);
  o[0] += b[0] + bf2f(rr4.x);
  o[1] += b[1] + bf2f(rr4.y);
  o[2] += b[2] + bf2f(rr4.z);
  o[3] += b[3] + bf2f(rr4.w);
  *(f32x4*)(out + idx) = o;
}

// ---------------- flash attention, split-K=4: grid (32, 12, 4), 4 waves x 32 q-rows ----------------
// QK^T C pre-initialized to -m_prev (defer-max); __all(lane_max <= 8) defer check (no shuffles);
// row-sum via mfma(ones, P); fp32 O partials; s_setprio(1) around MFMA clusters.
__global__ __launch_bounds__(256, 4) void flash_attn(const ushort* __restrict__ Qs,
                                                     const ushort* __restrict__ Ks,
                                                     const ushort* __restrict__ Vt,
                                                     float* __restrict__ Opart,
                                                     float* __restrict__ Ml){
  __shared__ __align__(16) char smem[32768];   // 2 bufs x (K 8KB + V 8KB)
  const int h = blockIdx.y, kh = blockIdx.z;
  const int w = threadIdx.x >> 6, l = threadIdx.x & 63;
  const int lr = l & 15, lg = l >> 4;
  const int lane8 = l >> 3, sl = l & 7;
  const int q0 = blockIdx.x * 128 + w * 32;
  const ushort* Qh = Qs + (size_t)h * (4096 * 64);
  const char* Kh = (const char*)(Ks + (size_t)h * (4096 * 64));
  const char* Vh = (const char*)(Vt + (size_t)h * (64 * 4096));

  bf16x8 qa[2][2];
  #pragma unroll
  for (int qf = 0; qf < 2; ++qf)
    #pragma unroll
    for (int kk = 0; kk < 2; ++kk)
      qa[qf][kk] = *(const bf16x8*)(Qh + (size_t)(q0 + qf * 16 + lr) * 64 + kk * 32 + lg * 8);

  // staging bases (inverse-swizzled source, T21)
  const char* kbase = Kh + (size_t)(kh * 1024 + w * 16 + lane8) * 128;
  const char* vbase = Vh + (size_t)(w * 16 + lane8) * 8192 + kh * 2048 + ((sl ^ lane8) << 4);
  int koff[2];
  #pragma unroll
  for (int j = 0; j < 2; ++j)
    koff[j] = j * 1024 + ((sl ^ ((lane8 & 3) | (((w * 2 + j) & 1) << 2))) << 4);

  // LDS read offsets (hoisted; K swizzle slot is t-independent)
  const int a_ = lr >> 2, b_ = lr & 3;
  const int krow = 8 * a_ + b_;                 // permuted K-row base
  const int f_ = b_ | ((a_ & 1) << 2);
  const int kslot0 = (lg ^ f_) << 4;
  const int kslot1 = ((4 + lg) ^ f_) << 4;
  const int vslot0 = lr * 128 + ((lg ^ (lr & 7)) << 4);
  const int vslot1 = lr * 128 + (((4 + lg) ^ (lr & 7)) << 4);

  f32x4 oacc[2][4] = {};        // C[d = db*16 + 4lg + r][q = lr] per qf
  f32x4 lacc[2] = {};           // row-sum accumulator
  float m_prev[2] = {0.0f, 0.0f};
  union { unsigned u[4]; bf16x8 v; } ones;
  #pragma unroll
  for (int i = 0; i < 4; ++i) ones.u[i] = 0x3F803F80u;

  auto stage = [&](int tile, char* Kb, char* Vb){
    #pragma unroll
    for (int j = 0; j < 2; ++j){
      gload_lds16(kbase + (size_t)tile * 8192 + koff[j], Kb + (w * 2 + j) * 1024);
      gload_lds16(vbase + (size_t)j * 65536 + (size_t)tile * 128, Vb + (w * 2 + j) * 1024);
    }
  };

  auto compute = [&](const char* Kb, const char* Vb, bool first){
    f32x4 sh[2][4];
    #pragma unroll
    for (int qf = 0; qf < 2; ++qf){
      float iv = first ? 0.0f : -m_prev[qf];
      #pragma unroll
      for (int t = 0; t < 4; ++t){
        sh[qf][t][0] = iv; sh[qf][t][1] = iv; sh[qf][t][2] = iv; sh[qf][t][3] = iv;
      }
    }
    __builtin_amdgcn_s_setprio(1);
    #pragma unroll
    for (int t = 0; t < 4; ++t){
      const char* kr = Kb + (krow + 4 * (t & 1) + 32 * (t >> 1)) * 128;
      bf16x8 k0 = *(const bf16x8*)(kr + kslot0);
      bf16x8 k1 = *(const bf16x8*)(kr + kslot1);
      #pragma unroll
      for (int qf = 0; qf < 2; ++qf){
        sh[qf][t] = __builtin_amdgcn_mfma_f32_16x16x32_bf16(k0, qa[qf][0], sh[qf][t], 0, 0, 0);
        sh[qf][t] = __builtin_amdgcn_mfma_f32_16x16x32_bf16(k1, qa[qf][1], sh[qf][t], 0, 0, 0);
      }
    }
    __builtin_amdgcn_s_setprio(0);
    // lane-local max per qf (16 values, 7 max ops) — no shuffles
    float mb[2];
    #pragma unroll
    for (int qf = 0; qf < 2; ++qf){
      float m1 = fmax3(sh[qf][0][0], sh[qf][0][1], sh[qf][0][2]);
      float m2 = fmax3(sh[qf][0][3], sh[qf][1][0], sh[qf][1][1]);
      float m3 = fmax3(sh[qf][1][2], sh[qf][1][3], sh[qf][2][0]);
      float m4 = fmax3(sh[qf][2][1], sh[qf][2][2], sh[qf][2][3]);
      float m5 = fmax3(sh[qf][3][0], sh[qf][3][1], sh[qf][3][2]);
      mb[qf] = fmax3(fmaxf(m1, m2), fmax3(m3, m4, m5), sh[qf][3][3]);
    }
    if (first){
      #pragma unroll
      for (int qf = 0; qf < 2; ++qf){
        float mm = fmaxf(mb[qf], __shfl_xor(mb[qf], 16, 64));
        mm = fmaxf(mm, __shfl_xor(mm, 32, 64));
        m_prev[qf] = mm;
        #pragma unroll
        for (int t = 0; t < 4; ++t)
          #pragma unroll
          for (int r = 0; r < 4; ++r) sh[qf][t][r] -= mm;
      }
    } else if (!__all(mb[0] <= 8.0f && mb[1] <= 8.0f)){
      #pragma unroll
      for (int qf = 0; qf < 2; ++qf){
        float mm = fmaxf(mb[qf], __shfl_xor(mb[qf], 16, 64));
        mm = fmaxf(mm, __shfl_xor(mm, 32, 64));
        float d = (mm > 8.0f) ? mm : 0.0f;       // sh already = S - m_prev
        float sc = exp2f(-d);
        #pragma unroll
        for (int t = 0; t < 4; ++t)
          #pragma unroll
          for (int r = 0; r < 4; ++r) sh[qf][t][r] -= d;
        #pragma unroll
        for (int db = 0; db < 4; ++db)
          #pragma unroll
          for (int r = 0; r < 4; ++r) oacc[qf][db][r] *= sc;
        #pragma unroll
        for (int r = 0; r < 4; ++r) lacc[qf][r] *= sc;
        m_prev[qf] += d;
      }
    }
    #pragma unroll
    for (int qf = 0; qf < 2; ++qf)
      #pragma unroll
      for (int t = 0; t < 4; ++t)
        #pragma unroll
        for (int r = 0; r < 4; ++r)
          sh[qf][t][r] = exp2f(sh[qf][t][r]);     // Q pre-scaled by log2e
    #pragma unroll
    for (int kk = 0; kk < 2; ++kk){
      union { unsigned u[4]; bf16x8 v; } pf[2];
      #pragma unroll
      for (int qf = 0; qf < 2; ++qf){
        pf[qf].u[0] = cvt_pk_bf16(sh[qf][2*kk][0],   sh[qf][2*kk][1]);
        pf[qf].u[1] = cvt_pk_bf16(sh[qf][2*kk][2],   sh[qf][2*kk][3]);
        pf[qf].u[2] = cvt_pk_bf16(sh[qf][2*kk+1][0], sh[qf][2*kk+1][1]);
        pf[qf].u[3] = cvt_pk_bf16(sh[qf][2*kk+1][2], sh[qf][2*kk+1][3]);
      }
      const int vs = kk ? vslot1 : vslot0;
      __builtin_amdgcn_s_setprio(1);
      #pragma unroll
      for (int db = 0; db < 4; ++db){
        bf16x8 vf = *(const bf16x8*)(Vb + vs + db * 2048);
        #pragma unroll
        for (int qf = 0; qf < 2; ++qf)
          oacc[qf][db] = __builtin_amdgcn_mfma_f32_16x16x32_bf16(vf, pf[qf].v, oacc[qf][db], 0, 0, 0);
      }
      #pragma unroll
      for (int qf = 0; qf < 2; ++qf)
        lacc[qf] = __builtin_amdgcn_mfma_f32_16x16x32_bf16(ones.v, pf[qf].v, lacc[qf], 0, 0, 0);
      __builtin_amdgcn_s_setprio(0);
    }
  };

  char* K0 = smem;          char* V0 = smem + 8192;
  char* K1 = smem + 16384;  char* V1 = smem + 24576;

  stage(0, K0, V0);
  __syncthreads();
  stage(1, K1, V1);
  compute(K0, V0, true);
  __syncthreads();
  stage(2, K0, V0);
  compute(K1, V1, false);
  __syncthreads();
  #pragma unroll 1
  for (int it2 = 1; it2 < 8; ++it2){             // 16 tiles = 1024 keys per segment
    stage(2 * it2 + 1, K1, V1);
    compute(K0, V0, false);
    __syncthreads();
    if (it2 < 7) stage(2 * it2 + 2, K0, V0);
    compute(K1, V1, false);
    __syncthreads();
  }

  #pragma unroll
  for (int qf = 0; qf < 2; ++qf){
    int q = q0 + qf * 16 + lr;
    float* Op = Opart + ((size_t)(kh * 12 + h) * 4096 + q) * 64;
    #pragma unroll
    for (int db = 0; db < 4; ++db)
      *(f32x4*)(Op + db * 16 + 4 * lg) = oacc[qf][db];
    if (lg == 0){
      float2 ml; ml.x = m_prev[qf]; ml.y = lacc[qf][0];
      *(float2*)(Ml + ((size_t)(kh * 12 + h) * 4096 + q) * 2) = ml;
    }
  }
}

// ---------------- split-K=4 attention combine (fp32 partials) ----------------
__global__ __launch_bounds__(192) void attn_combine(const float* __restrict__ Opart,
                                                    const float* __restrict__ Ml,
                                                    ushort* __restrict__ O){
  int q = blockIdx.x, t = threadIdx.x;           // t in [0,192): h = t>>4, d = (t&15)*4
  int h = t >> 4;
  float2 ml[4];
  float m = -1e30f;
  #pragma unroll
  for (int s = 0; s < 4; ++s){
    ml[s] = *(const float2*)(Ml + ((size_t)(s * 12 + h) * 4096 + q) * 2);
    m = fmaxf(m, ml[s].x);
  }
  float wgt[4], lsum = 0.0f;
  #pragma unroll
  for (int s = 0; s < 4; ++s){
    wgt[s] = exp2f(ml[s].x - m);
    lsum += ml[s].y * wgt[s];
  }
  float inv = 1.0f / lsum;
  int dd = (t & 15) * 4;
  f32x4 o = {};
  #pragma unroll
  for (int s = 0; s < 4; ++s){
    f32x4 os = *(const f32x4*)(Opart + ((size_t)(s * 12 + h) * 4096 + q) * 64 + dd);
    #pragma unroll
    for (int r = 0; r < 4; ++r) o[r] += os[r] * wgt[s];
  }
  uint2 ov;
  ov.x = cvt_pk_bf16(o[0] * inv, o[1] * inv);
  ov.y = cvt_pk_bf16(o[2] * inv, o[3] * inv);
  *(uint2*)(O + (size_t)q * 768 + t * 4) = ov;
}

// ---------------- launch ----------------
extern "C" void kernel_launch(void* const* d_in, const int* in_sizes, int n_in,
                              void* d_out, int out_size, void* d_ws, size_t ws_size,
                              hipStream_t stream){
  const float* x      = (const float*)d_in[0];
  const float* fcos   = (const float*)d_in[1];
  const float* fsin   = (const float*)d_in[2];
  const float* w_qkv  = (const float*)d_in[3];
  const float* w_proj = (const float*)d_in[4];
  const float* b_proj = (const float*)d_in[5];
  const float* g1     = (const float*)d_in[6];
  const float* beta1  = (const float*)d_in[7];
  const float* g2     = (const float*)d_in[8];
  const float* beta2  = (const float*)d_in[9];
  const float* w_fc1  = (const float*)d_in[10];
  const float* b_fc1  = (const float*)d_in[11];
  const float* w_fc2  = (const float*)d_in[12];
  const float* b_fc2  = (const float*)d_in[13];

  char* ws = (char*)d_ws;
  size_t off = 0;
  auto alloc = [&](size_t bytes) -> char* {
    char* p = ws + off; off += (bytes + 255) & ~(size_t)255; return p;
  };
  ushort* wq  = (ushort*)alloc((size_t)2304 * 768 * 2);
  ushort* wp  = (ushort*)alloc((size_t)768 * 768 * 2);
  ushort* w1  = (ushort*)alloc((size_t)3072 * 768 * 2);
  ushort* w2  = (ushort*)alloc((size_t)768 * 3072 * 2);
  ushort* h1  = (ushort*)alloc((size_t)4096 * 768 * 2);
  ushort* Qs  = (ushort*)alloc((size_t)12 * 4096 * 64 * 2);
  ushort* Ks  = (ushort*)alloc((size_t)12 * 4096 * 64 * 2);
  ushort* Vt  = (ushort*)alloc((size_t)12 * 64 * 4096 * 2);
  ushort* ao  = (ushort*)alloc((size_t)4096 * 768 * 2);
  ushort* x2b = (ushort*)alloc((size_t)4096 * 768 * 2);   // bf16 residual stream
  ushort* h2  = (ushort*)alloc((size_t)4096 * 768 * 2);
  ushort* f1  = (ushort*)alloc((size_t)4096 * 3072 * 2);
  float*  Opart = (float*)alloc((size_t)4 * 12 * 4096 * 64 * 4);
  float*  Ml    = (float*)alloc((size_t)4 * 12 * 4096 * 2 * 4);
  ushort* skp16 = (ushort*)Opart;   // alias: fc2 bf16 partials (24MB) reuse Opart once dead

  // fused prep: LN1 (1024 blocks) + all 4 weight conversions (6912 blocks)
  const int c0 = 2304*768/4, c1 = 768*768/4, c2 = 3072*768/4, c3 = 768*3072/4;
  const int cvt_blocks = (c0 + c1 + c2 + c3 + 255) / 256;
  prep_kernel<<<1024 + cvt_blocks, 256, 0, stream>>>(
      x, g1, beta1, h1,
      w_qkv, wq, c0, w_proj, wp, c1, w_fc1, w1, c2, w_fc2, w2, c3);

  // QKV GEMM with fused RoPE + per-head scatter (MODE 4)
  gemm_bf16<4><<<dim3(32, 18), 256, 0, stream>>>(h1, 768, wq, 768, 768,
                                                 nullptr, nullptr, 0, nullptr, 0,
                                                 fcos, fsin, Qs, Ks, Vt);
  // attention (split-K over 4 segments) + combine
  flash_attn<<<dim3(32, 12, 4), 256, 0, stream>>>(Qs, Ks, Vt, Opart, Ml);
  attn_combine<<<4096, 192, 0, stream>>>(Opart, Ml, ao);
  // proj + residual -> bf16 residual stream: x2b = bf16(x + ao @ w_proj^T + b_proj)  (MODE 6)
  gemm_bf16<6><<<dim3(32, 6), 256, 0, stream>>>(ao, 768, wp, 768, 768,
                                                b_proj, x, 768, x2b, 768,
                                                nullptr, nullptr, nullptr, nullptr, nullptr);
  // LN2 (bf16 in)
  ln_kernel_bf16<<<1024, 256, 0, stream>>>(x2b, g2, beta2, h2);
  // fc1 + fast GELU: f1 = gelu(h2 @ w_fc1^T + b_fc1)  (bf16)
  gemm_bf16<2><<<dim3(32, 24), 256, 0, stream>>>(h2, 768, w1, 768, 768,
                                                 b_fc1, nullptr, 0, f1, 3072,
                                                 nullptr, nullptr, nullptr, nullptr, nullptr);
  // fc2 split-K=4 with BF16 partials (MODE 5), then combine + bias + bf16 residual -> fp32 out
  gemm_bf16<5><<<dim3(32, 6, 4), 256, 0, stream>>>(f1, 3072, w2, 3072, 768,
                                                   nullptr, nullptr, 0, skp16, 768,
                                                   nullptr, nullptr, nullptr, nullptr, nullptr);
  gemm_combine4_bf16<<<4096, 192, 0, stream>>>(skp16, b_fc2, x2b, (float*)d_out);
}